// Round 3
// baseline (3881.771 us; speedup 1.0000x reference)
//
#include <hip/hip_runtime.h>
#include <hip/hip_bf16.h>

typedef __hip_bfloat16 bf16;
typedef __bf16 bf16x8 __attribute__((ext_vector_type(8)));
typedef float f32x4 __attribute__((ext_vector_type(4)));

static constexpr int TOKS = 2048;   // B*S
static constexpr int DM   = 2048;   // model dim
static constexpr int HD_  = 128;    // head dim
static constexpr int RL   = 512;    // MLA latent rank
static constexpr int DF   = 1024;   // FFN inter dim
static constexpr int NE_  = 4;      // experts
static constexpr int SQ   = 1024;   // seq len
static constexpr int NV   = 32000;  // vocab

__device__ __forceinline__ float b2f(bf16 x){ return __bfloat162float(x); }
__device__ __forceinline__ bf16  f2b(float x){ return __float2bfloat16(x); }

__device__ __forceinline__ void split1(float x, unsigned short& h, unsigned short& l){
  bf16 hb = f2b(x);
  float r = x - b2f(hb);
  bf16 lb = f2b(r);
  h = *(unsigned short*)&hb; l = *(unsigned short*)&lb;
}

// ---- block-wide reduction (256 threads = 4 waves), op: 0=sum 1=max ----
__device__ __forceinline__ float block_red(float v, int op){
  __shared__ float red[4];
  const int lane = threadIdx.x & 63, wv = threadIdx.x >> 6;
  #pragma unroll
  for (int off = 32; off > 0; off >>= 1){
    float o = __shfl_down(v, off, 64);
    v = op ? fmaxf(v, o) : v + o;
  }
  __syncthreads();
  if (lane == 0) red[wv] = v;
  __syncthreads();
  float r = red[0];
  #pragma unroll
  for (int i = 1; i < 4; ++i) r = op ? fmaxf(r, red[i]) : r + red[i];
  return r;
}

// ---- embedding gather (f32) + rmsnorm -> f32 residual ----
__global__ __launch_bounds__(256)
void embed_norm_k(const int* __restrict__ toks, const float* __restrict__ emb,
                  const float* __restrict__ w, float* __restrict__ h){
  const int t = blockIdx.x;
  const long tok = toks[t];
  const int base = threadIdx.x * 8;
  const float* ep = emb + tok * (long)DM + base;
  float4 va = *(const float4*)ep, vb = *(const float4*)(ep + 4);
  float v[8] = {va.x, va.y, va.z, va.w, vb.x, vb.y, vb.z, vb.w};
  float ss = 0.f;
  #pragma unroll
  for (int i = 0; i < 8; ++i) ss += v[i]*v[i];
  ss = block_red(ss, 0);
  const float inv = rsqrtf(ss / DM + 1e-6f);
  float4 wa = *(const float4*)(w + base), wb = *(const float4*)(w + base + 4);
  float wv[8] = {wa.x, wa.y, wa.z, wa.w, wb.x, wb.y, wb.z, wb.w};
  float* hp = h + (long)t * DM + base;
  #pragma unroll
  for (int i = 0; i < 8; ++i) hp[i] = v[i] * inv * wv[i];
}

// ---- rmsnorm f32 residual -> f32 normed ----
__global__ __launch_bounds__(256)
void rmsnormf_k(const float* __restrict__ h, const float* __restrict__ w, float* __restrict__ o){
  const int t = blockIdx.x;
  const int base = threadIdx.x * 8;
  const float* hp = h + (long)t * DM + base;
  float4 va = *(const float4*)hp, vb = *(const float4*)(hp + 4);
  float v[8] = {va.x, va.y, va.z, va.w, vb.x, vb.y, vb.z, vb.w};
  float ss = 0.f;
  #pragma unroll
  for (int i = 0; i < 8; ++i) ss += v[i]*v[i];
  ss = block_red(ss, 0);
  const float inv = rsqrtf(ss / DM + 1e-6f);
  float4 wa = *(const float4*)(w + base), wb = *(const float4*)(w + base + 4);
  float wv[8] = {wa.x, wa.y, wa.z, wa.w, wb.x, wb.y, wb.z, wb.w};
  float* op = o + (long)t * DM + base;
  #pragma unroll
  for (int i = 0; i < 8; ++i) op[i] = v[i] * inv * wv[i];
}

// ---- rmsnorm f32 residual -> bf16 ----
__global__ __launch_bounds__(256)
void rmsnorm_k(const float* __restrict__ h, const float* __restrict__ w, bf16* __restrict__ o){
  const int t = blockIdx.x;
  const int base = threadIdx.x * 8;
  const float* hp = h + (long)t * DM + base;
  float4 va = *(const float4*)hp, vb = *(const float4*)(hp + 4);
  float v[8] = {va.x, va.y, va.z, va.w, vb.x, vb.y, vb.z, vb.w};
  float ss = 0.f;
  #pragma unroll
  for (int i = 0; i < 8; ++i) ss += v[i]*v[i];
  ss = block_red(ss, 0);
  const float inv = rsqrtf(ss / DM + 1e-6f);
  float4 wa = *(const float4*)(w + base), wb = *(const float4*)(w + base + 4);
  float wv[8] = {wa.x, wa.y, wa.z, wa.w, wb.x, wb.y, wb.z, wb.w};
  union { int4 i4; bf16 b[8]; } ob;
  #pragma unroll
  for (int i = 0; i < 8; ++i) ob.b[i] = f2b(v[i] * inv * wv[i]);
  *(int4*)(o + (long)t * DM + base) = ob.i4;
}

// ---- row softmax over 1024 f32, in place ----
__global__ __launch_bounds__(256)
void softmaxf_k(float* __restrict__ p){
  float* pr = p + (long)blockIdx.x * SQ;
  const int base = threadIdx.x * 4;
  float4 v4 = *(const float4*)(pr + base);
  float v[4] = {v4.x, v4.y, v4.z, v4.w};
  float m = fmaxf(fmaxf(v[0], v[1]), fmaxf(v[2], v[3]));
  m = block_red(m, 1);
  float s = 0.f;
  #pragma unroll
  for (int i = 0; i < 4; ++i){ v[i] = expf(v[i] - m); s += v[i]; }
  s = block_red(s, 0);
  const float inv = 1.f / s;
  float4 o4 = {v[0]*inv, v[1]*inv, v[2]*inv, v[3]*inv};
  *(float4*)(pr + base) = o4;
}

// ---- MoE gate in full f32 (rmsnorm fused): top-2, normalized -> gw[T][4] ----
__global__ __launch_bounds__(256)
void gate_k(const float* __restrict__ h, const float* __restrict__ nw,
            const float* __restrict__ Wg, float* __restrict__ gw){
  const int t = blockIdx.x;
  const int base = threadIdx.x * 8;
  const float* hp = h + (long)t * DM + base;
  float4 va = *(const float4*)hp, vb = *(const float4*)(hp + 4);
  float v[8] = {va.x, va.y, va.z, va.w, vb.x, vb.y, vb.z, vb.w};
  float ss = 0.f;
  #pragma unroll
  for (int i = 0; i < 8; ++i) ss += v[i]*v[i];
  ss = block_red(ss, 0);
  const float inv = rsqrtf(ss / DM + 1e-6f);
  float a[4] = {0.f, 0.f, 0.f, 0.f};
  #pragma unroll
  for (int i = 0; i < 8; ++i){
    const float xv = v[i] * inv * nw[base + i];
    #pragma unroll
    for (int e = 0; e < 4; ++e) a[e] += xv * Wg[(base + i)*4 + e];
  }
  #pragma unroll
  for (int e = 0; e < 4; ++e) a[e] = block_red(a[e], 0);
  if (threadIdx.x == 0){
    // top-2 by logits (same order as softmax values); lowest index wins ties
    int i1 = 0;
    for (int e = 1; e < 4; ++e) if (a[e] > a[i1]) i1 = e;
    int i2 = -1;
    for (int e = 0; e < 4; ++e){ if (e == i1) continue; if (i2 < 0 || a[e] > a[i2]) i2 = e; }
    float g[4];
    const float m = fmaxf(fmaxf(a[0], a[1]), fmaxf(a[2], a[3]));
    float s = 0.f;
    for (int e = 0; e < 4; ++e){ g[e] = __expf(a[e] - m); s += g[e]; }
    for (int e = 0; e < 4; ++e) g[e] /= s;
    const float ns = g[i1] + g[i2];
    float* op = gw + (long)t * 4;
    op[0] = 0.f; op[1] = 0.f; op[2] = 0.f; op[3] = 0.f;
    op[i1] = g[i1] / ns; op[i2] = g[i2] / ns;
  }
}

// ---- swiglu f32: h1 = silu(h1) * h3 ----
__global__ __launch_bounds__(256)
void swigluf_k(float* __restrict__ h1, const float* __restrict__ h3){
  const long i = ((long)blockIdx.x * 256 + threadIdx.x) * 4;
  float4 x = *(const float4*)(h1 + i);
  float4 y = *(const float4*)(h3 + i);
  float a[4] = {x.x, x.y, x.z, x.w}, b[4] = {y.x, y.y, y.z, y.w};
  #pragma unroll
  for (int j = 0; j < 4; ++j) a[j] = (a[j] / (1.f + expf(-a[j]))) * b[j];
  float4 o = {a[0], a[1], a[2], a[3]};
  *(float4*)(h1 + i) = o;
}

// ---- swiglu bf16: h1 = silu(h1) * h3 ----
__global__ __launch_bounds__(256)
void swiglu_k(bf16* __restrict__ h1, const bf16* __restrict__ h3){
  const long i = ((long)blockIdx.x * 256 + threadIdx.x) * 8;
  union { int4 i4; bf16 b[8]; } x, y;
  x.i4 = *(const int4*)(h1 + i);
  y.i4 = *(const int4*)(h3 + i);
  #pragma unroll
  for (int j = 0; j < 8; ++j){
    const float a = b2f(x.b[j]);
    const float b = b2f(y.b[j]);
    x.b[j] = f2b((a / (1.f + __expf(-a))) * b);
  }
  *(int4*)(h1 + i) = x.i4;
}

static constexpr int KP = 40;
__device__ __forceinline__ int swz(int row, int col){
  return ((((col >> 3) + (row >> 3)) & 3) << 3) | (col & 7);
}

// ==== SPLIT-PRECISION GEMM (~f32 accuracy via bf16 hi/lo, 3 MFMA) ====
// C[M,N] = A[M,K] (f32) * B (f32).  BNT=1: B=[N,K].  BNT=0: B=[K,N].
// OM: 0 = f32 store*scale, 1 = f32 +=, 3 = f32 += gate[row]*v
template<int BNT, int OM>
__global__ __launch_bounds__(256)
void gemmx_k(const float* __restrict__ A, long ab, int lda,
             const float* __restrict__ B, long bb, int ldb,
             float* __restrict__ C, long cb, int ldc,
             int K, float scale, const float* __restrict__ gate, int gst)
{
  __shared__ __align__(16) unsigned short ah[128][KP], al[128][KP];
  __shared__ __align__(16) unsigned short bh[128][KP], bl[128][KP];
  const float* Ab = A + (long)blockIdx.z * ab;
  const float* Bb = B + (long)blockIdx.z * bb;
  const int m0 = blockIdx.y * 128, n0 = blockIdx.x * 128;
  const int tid = threadIdx.x, lane = tid & 63, wid = tid >> 6;
  const int wr = (wid >> 1) * 64, wc = (wid & 1) * 64;
  const int fr = lane & 15, fk = (lane >> 4) * 8;

  f32x4 acc[4][4] = {};

  for (int k0 = 0; k0 < K; k0 += 32){
    __syncthreads();
    #pragma unroll
    for (int p = 0; p < 2; ++p){
      const int idx = p * 256 + tid;
      const int r = idx >> 2, c = (idx & 3) * 8;
      const float* ap = Ab + (long)(m0 + r) * lda + k0 + c;
      const float4 va = *(const float4*)ap, vb = *(const float4*)(ap + 4);
      const float q[8] = {va.x, va.y, va.z, va.w, vb.x, vb.y, vb.z, vb.w};
      unsigned short hi[8], lo[8];
      #pragma unroll
      for (int i = 0; i < 8; ++i) split1(q[i], hi[i], lo[i]);
      *(int4*)&ah[r][swz(r, c)] = *(const int4*)hi;
      *(int4*)&al[r][swz(r, c)] = *(const int4*)lo;
    }
    if (BNT){
      #pragma unroll
      for (int p = 0; p < 2; ++p){
        const int idx = p * 256 + tid;
        const int r = idx >> 2, c = (idx & 3) * 8;
        const float* bp = Bb + (long)(n0 + r) * ldb + k0 + c;
        const float4 va = *(const float4*)bp, vb = *(const float4*)(bp + 4);
        const float q[8] = {va.x, va.y, va.z, va.w, vb.x, vb.y, vb.z, vb.w};
        unsigned short hi[8], lo[8];
        #pragma unroll
        for (int i = 0; i < 8; ++i) split1(q[i], hi[i], lo[i]);
        *(int4*)&bh[r][swz(r, c)] = *(const int4*)hi;
        *(int4*)&bl[r][swz(r, c)] = *(const int4*)lo;
      }
    } else {
      const int kr = (tid >> 4) * 2, nc = (tid & 15) * 8;
      const float* bp = Bb + (long)(k0 + kr) * ldb + n0 + nc;
      const float4 r0a = *(const float4*)bp,         r0b = *(const float4*)(bp + 4);
      const float4 r1a = *(const float4*)(bp + ldb), r1b = *(const float4*)(bp + ldb + 4);
      const float q0[8] = {r0a.x, r0a.y, r0a.z, r0a.w, r0b.x, r0b.y, r0b.z, r0b.w};
      const float q1[8] = {r1a.x, r1a.y, r1a.z, r1a.w, r1b.x, r1b.y, r1b.z, r1b.w};
      #pragma unroll
      for (int i = 0; i < 8; ++i){
        const int n = nc + i;
        unsigned short h0, l0, h1, l1;
        split1(q0[i], h0, l0); split1(q1[i], h1, l1);
        *(unsigned int*)&bh[n][swz(n, kr)] = (unsigned int)h0 | ((unsigned int)h1 << 16);
        *(unsigned int*)&bl[n][swz(n, kr)] = (unsigned int)l0 | ((unsigned int)l1 << 16);
      }
    }
    __syncthreads();
    bf16x8 ahf[4], alf[4], bhf[4], blf[4];
    #pragma unroll
    for (int mi = 0; mi < 4; ++mi){
      const int rr = wr + mi * 16 + fr;
      ahf[mi] = *(const bf16x8*)&ah[rr][swz(rr, fk)];
      alf[mi] = *(const bf16x8*)&al[rr][swz(rr, fk)];
    }
    #pragma unroll
    for (int ni = 0; ni < 4; ++ni){
      const int rr = wc + ni * 16 + fr;
      bhf[ni] = *(const bf16x8*)&bh[rr][swz(rr, fk)];
      blf[ni] = *(const bf16x8*)&bl[rr][swz(rr, fk)];
    }
    #pragma unroll
    for (int mi = 0; mi < 4; ++mi)
      #pragma unroll
      for (int ni = 0; ni < 4; ++ni){
        acc[mi][ni] = __builtin_amdgcn_mfma_f32_16x16x32_bf16(ahf[mi], bhf[ni], acc[mi][ni], 0, 0, 0);
        acc[mi][ni] = __builtin_amdgcn_mfma_f32_16x16x32_bf16(ahf[mi], blf[ni], acc[mi][ni], 0, 0, 0);
        acc[mi][ni] = __builtin_amdgcn_mfma_f32_16x16x32_bf16(alf[mi], bhf[ni], acc[mi][ni], 0, 0, 0);
      }
  }

  const int crow = (lane >> 4) * 4, ccol = lane & 15;
  const long cbz = (long)blockIdx.z * cb;
  #pragma unroll
  for (int mi = 0; mi < 4; ++mi){
    #pragma unroll
    for (int ni = 0; ni < 4; ++ni){
      const int gm = m0 + wr + mi * 16 + crow;
      const int gn = n0 + wc + ni * 16 + ccol;
      #pragma unroll
      for (int j = 0; j < 4; ++j){
        const long off = cbz + (long)(gm + j) * ldc + gn;
        const float v = acc[mi][ni][j];
        if (OM == 0)      C[off] = v * scale;
        else if (OM == 1) C[off] += v;
        else              C[off] += gate[(long)(gm + j) * gst] * v;
      }
    }
  }
}

// ==== PLAIN BF16 GEMM (output-only paths) ====
// A bf16 [M,K]; B f32 [K,N] converted during staging.
// OM: 0 = bf16 store, 2 = f32 store + f32 bias, 3 = f32 += gate[row]*v
template<int OM>
__global__ __launch_bounds__(256)
void gemm_k(const bf16* __restrict__ A, long ab, int lda,
            const float* __restrict__ B, long bb, int ldb,
            void* __restrict__ Cv, long cb, int ldc,
            int K, const float* __restrict__ bias, const float* __restrict__ gate, int gst)
{
  __shared__ __align__(16) bf16 a_lds[128][KP];
  __shared__ __align__(16) bf16 b_lds[128][KP];
  const bf16* Ab = A + (long)blockIdx.z * ab;
  const float* Bb = B + (long)blockIdx.z * bb;
  const int m0 = blockIdx.y * 128, n0 = blockIdx.x * 128;
  const int tid = threadIdx.x, lane = tid & 63, wid = tid >> 6;
  const int wr = (wid >> 1) * 64, wc = (wid & 1) * 64;
  const int fr = lane & 15, fk = (lane >> 4) * 8;

  f32x4 acc[4][4] = {};

  for (int k0 = 0; k0 < K; k0 += 32){
    __syncthreads();
    #pragma unroll
    for (int p = 0; p < 2; ++p){
      const int idx = p * 256 + tid;
      const int r = idx >> 2, c = (idx & 3) * 8;
      const int4 v4 = *(const int4*)(Ab + (long)(m0 + r) * lda + k0 + c);
      *(int4*)&a_lds[r][swz(r, c)] = v4;
    }
    {
      const int kr = (tid >> 4) * 2, nc = (tid & 15) * 8;
      const float* bp = Bb + (long)(k0 + kr) * ldb + n0 + nc;
      const float4 r0a = *(const float4*)bp,         r0b = *(const float4*)(bp + 4);
      const float4 r1a = *(const float4*)(bp + ldb), r1b = *(const float4*)(bp + ldb + 4);
      const float q0[8] = {r0a.x, r0a.y, r0a.z, r0a.w, r0b.x, r0b.y, r0b.z, r0b.w};
      const float q1[8] = {r1a.x, r1a.y, r1a.z, r1a.w, r1b.x, r1b.y, r1b.z, r1b.w};
      #pragma unroll
      for (int i = 0; i < 8; ++i){
        const int n = nc + i;
        bf16 lo = f2b(q0[i]), hi = f2b(q1[i]);
        const unsigned int dv = (unsigned int)(*(unsigned short*)&lo)
                              | ((unsigned int)(*(unsigned short*)&hi) << 16);
        *(unsigned int*)&b_lds[n][swz(n, kr)] = dv;
      }
    }
    __syncthreads();
    bf16x8 af[4], bfv[4];
    #pragma unroll
    for (int mi = 0; mi < 4; ++mi){
      const int rr = wr + mi * 16 + fr;
      af[mi] = *(const bf16x8*)&a_lds[rr][swz(rr, fk)];
    }
    #pragma unroll
    for (int ni = 0; ni < 4; ++ni){
      const int rr = wc + ni * 16 + fr;
      bfv[ni] = *(const bf16x8*)&b_lds[rr][swz(rr, fk)];
    }
    #pragma unroll
    for (int mi = 0; mi < 4; ++mi)
      #pragma unroll
      for (int ni = 0; ni < 4; ++ni)
        acc[mi][ni] = __builtin_amdgcn_mfma_f32_16x16x32_bf16(af[mi], bfv[ni], acc[mi][ni], 0, 0, 0);
  }

  const int crow = (lane >> 4) * 4, ccol = lane & 15;
  const long cbz = (long)blockIdx.z * cb;
  #pragma unroll
  for (int mi = 0; mi < 4; ++mi){
    #pragma unroll
    for (int ni = 0; ni < 4; ++ni){
      const int gm = m0 + wr + mi * 16 + crow;
      const int gn = n0 + wc + ni * 16 + ccol;
      #pragma unroll
      for (int j = 0; j < 4; ++j){
        const long off = cbz + (long)(gm + j) * ldc + gn;
        const float v = acc[mi][ni][j];
        if (OM == 0)      ((bf16*)Cv)[off] = f2b(v);
        else if (OM == 2) ((float*)Cv)[off] = v + bias[gn];
        else              ((float*)Cv)[off] += gate[(long)(gm + j) * gst] * v;
      }
    }
  }
}

extern "C" void kernel_launch(void* const* d_in, const int* in_sizes, int n_in,
                              void* d_out, int out_size, void* d_ws, size_t ws_size,
                              hipStream_t stream)
{
  (void)in_sizes; (void)n_in; (void)out_size; (void)ws_size;
  const int*   toks = (const int*)d_in[0];
  const float* emb  = (const float*)d_in[1];
  const float* enw  = (const float*)d_in[2];
  const float* nw   = (const float*)d_in[3];
  const float* Wq   = (const float*)d_in[4];
  const float* Wdkv = (const float*)d_in[5];
  const float* Wuk  = (const float*)d_in[6];
  const float* Wuv  = (const float*)d_in[7];
  const float* Wo   = (const float*)d_in[8];
  const float* Wg   = (const float*)d_in[9];
  const float* W1   = (const float*)d_in[10];
  const float* W3   = (const float*)d_in[11];
  const float* W2   = (const float*)d_in[12];
  const float* hnw  = (const float*)d_in[13];
  const float* hW   = (const float*)d_in[14];
  const float* hb   = (const float*)d_in[15];

  const size_t MB = 1u << 20;
  char* ws = (char*)d_ws;
  float* h   = (float*)(ws);              // 0-16: residual f32
  float* xnf = (float*)(ws + 16*MB);      // 16-32: normed f32
  float* qf  = (float*)(ws + 32*MB);      // 32-48: q f32
  float* cf  = (float*)(ws + 48*MB);      // 48-52: latent f32
  float* kf  = (float*)(ws + 52*MB);      // 52-68: k f32
  float* vf  = (float*)(ws + 68*MB);      // 68-84: v f32
  float* of  = (float*)(ws + 84*MB);      // 84-100: attn out f32
  float* pf  = (float*)(ws + 100*MB);     // 100-116: probs f32, 4 heads/chunk
  float* h1f = (float*)(ws + 32*MB);      // 32-64: [E][T][DF] f32 (aliases qf/cf/kf; dead then)
  float* h3f = (float*)(ws + 64*MB);      // 64-96: (aliases vf/of; dead then)
  bf16*  h1b = (bf16*)(ws + 32*MB);       // moe2 bf16
  bf16*  h3b = (bf16*)(ws + 48*MB);
  bf16*  xnb = (bf16*)(ws + 116*MB);      // 116-124: bf16 normed
  float* gw  = (float*)(ws + 124*MB);     // gates [T][4]

  embed_norm_k<<<TOKS, 256, 0, stream>>>(toks, emb, enw, h);

  for (int l = 0; l < 2; ++l){
    const float* nwl = nw + (long)l * DM;
    rmsnormf_k<<<TOKS, 256, 0, stream>>>(h, nwl, xnf);
    gemmx_k<0,0><<<dim3(16,16,1), 256, 0, stream>>>(xnf, 0, DM, Wq + (long)l*DM*DM, 0, DM,
                                                    qf, 0, DM, DM, 1.f, nullptr, 0);
    gemmx_k<0,0><<<dim3(4,16,1), 256, 0, stream>>>(xnf, 0, DM, Wdkv + (long)l*DM*RL, 0, RL,
                                                   cf, 0, RL, DM, 1.f, nullptr, 0);
    gemmx_k<0,0><<<dim3(16,16,1), 256, 0, stream>>>(cf, 0, RL, Wuk + (long)l*RL*DM, 0, DM,
                                                    kf, 0, DM, RL, 1.f, nullptr, 0);
    gemmx_k<0,0><<<dim3(16,16,1), 256, 0, stream>>>(cf, 0, RL, Wuv + (long)l*RL*DM, 0, DM,
                                                    vf, 0, DM, RL, 1.f, nullptr, 0);
    for (int b = 0; b < 2; ++b){
      for (int hg = 0; hg < 4; ++hg){
        const long aoff = (long)b*SQ*DM + (long)hg*4*HD_;
        gemmx_k<1,0><<<dim3(8,8,4), 256, 0, stream>>>(qf + aoff, HD_, DM, kf + aoff, HD_, DM,
                                                      pf, (long)SQ*SQ, SQ,
                                                      HD_, 0.08838834764831845f, nullptr, 0);
        softmaxf_k<<<4*SQ, 256, 0, stream>>>(pf);
        gemmx_k<0,0><<<dim3(1,8,4), 256, 0, stream>>>(pf, (long)SQ*SQ, SQ, vf + aoff, HD_, DM,
                                                      of + aoff, HD_, DM, SQ, 1.f, nullptr, 0);
      }
    }
    gemmx_k<0,1><<<dim3(16,16,1), 256, 0, stream>>>(of, 0, DM, Wo + (long)l*DM*DM, 0, DM,
                                                    h, 0, DM, DM, 1.f, nullptr, 0);
    gate_k<<<TOKS, 256, 0, stream>>>(h, nwl, Wg + (long)l*DM*NE_, gw);
    if (l == 0){
      // precise MoE (feeds layer-2 gates)
      rmsnormf_k<<<TOKS, 256, 0, stream>>>(h, nwl, xnf);
      gemmx_k<0,0><<<dim3(8,16,4), 256, 0, stream>>>(xnf, 0, DM, W1 + (long)l*NE_*DM*DF, (long)DM*DF, DF,
                                                     h1f, (long)TOKS*DF, DF, DM, 1.f, nullptr, 0);
      gemmx_k<0,0><<<dim3(8,16,4), 256, 0, stream>>>(xnf, 0, DM, W3 + (long)l*NE_*DM*DF, (long)DM*DF, DF,
                                                     h3f, (long)TOKS*DF, DF, DM, 1.f, nullptr, 0);
      swigluf_k<<<8192, 256, 0, stream>>>(h1f, h3f);
      for (int e = 0; e < NE_; ++e){
        gemmx_k<0,3><<<dim3(16,16,1), 256, 0, stream>>>(h1f + (long)e*TOKS*DF, 0, DF,
                                                        W2 + ((long)l*NE_ + e)*DF*DM, 0, DM,
                                                        h, 0, DM, DF, 1.f, gw + e, NE_);
      }
    } else {
      // fast bf16 MoE (only feeds the output head)
      rmsnorm_k<<<TOKS, 256, 0, stream>>>(h, nwl, xnb);
      gemm_k<0><<<dim3(8,16,4), 256, 0, stream>>>(xnb, 0, DM, W1 + (long)l*NE_*DM*DF, (long)DM*DF, DF,
                                                  h1b, (long)TOKS*DF, DF, DM, nullptr, nullptr, 0);
      gemm_k<0><<<dim3(8,16,4), 256, 0, stream>>>(xnb, 0, DM, W3 + (long)l*NE_*DM*DF, (long)DM*DF, DF,
                                                  h3b, (long)TOKS*DF, DF, DM, nullptr, nullptr, 0);
      swiglu_k<<<4096, 256, 0, stream>>>(h1b, h3b);
      for (int e = 0; e < NE_; ++e){
        gemm_k<3><<<dim3(16,16,1), 256, 0, stream>>>(h1b + (long)e*TOKS*DF, 0, DF,
                                                     W2 + ((long)l*NE_ + e)*DF*DM, 0, DM,
                                                     h, 0, DM, DF, nullptr, gw + e, NE_);
      }
    }
  }

  rmsnorm_k<<<TOKS, 256, 0, stream>>>(h, hnw, xnb);
  gemm_k<2><<<dim3(250,16,1), 256, 0, stream>>>(xnb, 0, DM, hW, 0, NV,
                                                (float*)d_out, 0, NV, DM, hb, nullptr, 0);
}